// Round 5
// baseline (224.194 us; speedup 1.0000x reference)
//
#include <hip/hip_runtime.h>
#include <math.h>

#define BB 2
#define CC 256
#define LL 512   // H == W == L

typedef float v4f __attribute__((ext_vector_type(4)));

__device__ __forceinline__ float gelu_exact(float x) {
    return 0.5f * x * (1.0f + erff(x * 0.70710678118654752f));
}

// 1) gather diagonal: diag[bc*L + l] = feat[(bc*L + l)*L + l]
__global__ void k_gather(const float* __restrict__ feat, float* __restrict__ diag) {
    int idx = blockIdx.x * blockDim.x + threadIdx.x;  // B*C*L
    if (idx >= BB * CC * LL) return;
    int l = idx & (LL - 1);
    long long bc = idx >> 9;
    diag[idx] = feat[(bc * LL + l) * LL + l];
}

// 2) grouped conv1d (groups=8) + bias + exact GELU; 3 acc chains
__global__ void k_conv1(const float* __restrict__ diag, const float* __restrict__ w1,
                        const float* __restrict__ b1, float* __restrict__ x1) {
    int idx = blockIdx.x * blockDim.x + threadIdx.x;  // (b*C + o)*L + l, l fastest
    if (idx >= BB * CC * LL) return;
    int l = idx & (LL - 1);
    int o = (idx >> 9) & (CC - 1);
    int b = idx >> 17;
    const float* dg = diag + ((b * CC + ((o >> 5) << 5)) << 9);  // 32-ch group base
    const float* wp = w1 + o * 96;                               // wave-uniform
    float a0 = 0.f, a1 = 0.f, a2 = 0.f;
    bool hm = (l > 0), hp = (l < LL - 1);
    #pragma unroll
    for (int i = 0; i < 32; ++i) {
        const float* dc = dg + (i << 9);
        float dm = hm ? dc[l - 1] : 0.f;
        float d0 = dc[l];
        float dp = hp ? dc[l + 1] : 0.f;
        a0 += dm * wp[i * 3 + 0];
        a1 += d0 * wp[i * 3 + 1];
        a2 += dp * wp[i * 3 + 2];
    }
    x1[idx] = gelu_exact(a0 + a1 + a2 + b1[o]);
}

// 3) transpose w2 [o][c][k] -> w2t [(c*3+k)*C + o]
__global__ void k_transpose_w2(const float* __restrict__ w2, float* __restrict__ w2t) {
    int idx = blockIdx.x * blockDim.x + threadIdx.x;
    if (idx >= CC * CC * 3) return;
    int o = idx / 768;
    int ck = idx - o * 768;
    w2t[ck * CC + o] = w2[idx];
}

// 4) dense conv1d + bias + exact GELU
//    block = (b, l-tile of 8, o-chunk of 64); 512 blocks, 256 threads
#define TL2 8
__global__ __launch_bounds__(256) void k_conv2(const float* __restrict__ x1,
                                               const float* __restrict__ w2t,
                                               const float* __restrict__ b2,
                                               float* __restrict__ x2) {
    __shared__ float s[CC][TL2 + 2];
    int blk = blockIdx.x;
    int oc = blk & 3;
    int lt = (blk >> 2) & 63;
    int b  = blk >> 8;
    int l0 = lt * TL2;
    for (int t = threadIdx.x; t < CC * (TL2 + 2); t += 256) {
        int c = t / (TL2 + 2);
        int j = t - c * (TL2 + 2);
        int p = l0 + j - 1;
        s[c][j] = (p >= 0 && p < LL) ? x1[((b * CC + c) << 9) + p] : 0.0f;
    }
    __syncthreads();
    int o  = (oc << 6) + (threadIdx.x & 63);   // lanes: consecutive o -> coalesced w loads
    int jg = threadIdx.x >> 6;                 // wave-uniform -> LDS broadcasts
    float bias = b2[o];
    float acc0 = bias, acc1 = bias;
    const float* wp = w2t + o;
    #pragma unroll 4
    for (int c = 0; c < CC; ++c) {
        float w0  = wp[c * 768];
        float w1v = wp[c * 768 + 256];
        float w2v = wp[c * 768 + 512];
        float s0 = s[c][jg * 2 + 0];
        float s1 = s[c][jg * 2 + 1];
        float s2 = s[c][jg * 2 + 2];
        float s3 = s[c][jg * 2 + 3];
        acc0 += s0 * w0 + s1 * w1v + s2 * w2v;
        acc1 += s1 * w0 + s2 * w1v + s3 * w2v;
    }
    int l = l0 + jg * 2;
    float* xo = x2 + ((b * CC + o) << 9) + l;
    xo[0] = gelu_exact(acc0);
    xo[1] = gelu_exact(acc1);
}

// 5) fused writer in vendor-fill shape: one thread = one float4, no loop.
//    131072 blocks x 256 threads covers 2*256*512*512 floats exactly.
__global__ __launch_bounds__(256) void k_write(const float* __restrict__ x2,
                                               const float* __restrict__ wb,
                                               v4f* __restrict__ out) {
    int idx4 = blockIdx.x * 256 + threadIdx.x;     // < 33,554,432, fits int
    int row = idx4 >> 7;        // bc*512 + i
    int i   = row & (LL - 1);
    int d0  = ((idx4 & 127) << 2) - i;   // j0 - i
    v4f v = (v4f)(0.f);
    if ((unsigned)(d0 + 5) <= 7u) {      // quad intersects band |j-i|<=2
        int bc = row >> 9;
        const float* xr = x2 + (bc << 9);
        float xm = (i > 0)      ? xr[i - 1] : 0.f;
        float x0 = xr[i];
        float xp = (i < LL - 1) ? xr[i + 1] : 0.f;
        const float* w = wb + (bc & (CC - 1)) * 9;  // w_blur[c,0,ki,kj]
        #pragma unroll
        for (int t = 0; t < 4; ++t) {
            int d = d0 + t;
            float r = 0.f;
            if (d == -2)      r = w[2] * xm;
            else if (d == -1) r = w[1] * xm + w[5] * x0;
            else if (d == 0)  r = w[0] * xm + w[4] * x0 + w[8] * xp;
            else if (d == 1)  r = w[3] * x0 + w[7] * xp;
            else if (d == 2)  r = w[6] * xp;
            v[t] = r;
        }
    }
    out[idx4] = v;
}

extern "C" void kernel_launch(void* const* d_in, const int* in_sizes, int n_in,
                              void* d_out, int out_size, void* d_ws, size_t ws_size,
                              hipStream_t stream) {
    const float* feat   = (const float*)d_in[0];
    const float* w1     = (const float*)d_in[1];
    const float* b1     = (const float*)d_in[2];
    const float* w2     = (const float*)d_in[3];
    const float* b2     = (const float*)d_in[4];
    const float* w_blur = (const float*)d_in[5];
    float* out = (float*)d_out;
    float* ws  = (float*)d_ws;

    const int N = BB * CC * LL;      // 262144
    float* diag = ws;                // [N]
    float* x1   = ws + N;            // [N]
    float* x2   = ws + 2 * N;        // [N]
    float* w2t  = ws + 3 * N;        // [C*C*3]

    k_gather<<<N / 256, 256, 0, stream>>>(feat, diag);
    k_transpose_w2<<<(CC * CC * 3 + 255) / 256, 256, 0, stream>>>(w2, w2t);
    k_conv1<<<N / 256, 256, 0, stream>>>(diag, w1, b1, x1);
    k_conv2<<<BB * (LL / TL2) * 4, 256, 0, stream>>>(x1, w2t, b2, x2);
    k_write<<<(BB * CC * LL * (LL / 4)) / 256, 256, 0, stream>>>(x2, w_blur, (v4f*)out);
}

// Round 8
// 145.950 us; speedup vs baseline: 1.5361x; 1.5361x over previous
//
#include <hip/hip_runtime.h>
#include <math.h>

#define BB 2
#define CC 256
#define LL 512   // H == W == L

// quad partition of the 2^25 output float4s
#define N4       33554432
#define A_QUADS  11184896   // K1 zeros [0, A)            = 43691*256
#define B_QUADS  22369792   // K2 zeros [A, B)            = 43691*256 more
#define ZBLK     43691
#define K3_FUSED 43690      // K3 fused covers [B, N4)    = 43690*256
#define ROWS_LO  174764     // rows with all quads < B    (B/128)
#define BANDBLK  683        // ceil(ROWS_LO/256)

typedef float v4f __attribute__((ext_vector_type(4)));

__device__ __forceinline__ float gelu_exact(float x) {
    return 0.5f * x * (1.0f + erff(x * 0.70710678118654752f));
}

// ---------------- K1: fused diag-gather + grouped conv1 (+GELU) -> x1,
//                  w2 transpose -> w2t, and zero quads [0, A) ----------------
__global__ __launch_bounds__(256) void k1(
    const float* __restrict__ feat, const float* __restrict__ w1,
    const float* __restrict__ b1, const float* __restrict__ w2,
    float* __restrict__ x1, float* __restrict__ w2t, v4f* __restrict__ out)
{
    const int tid = threadIdx.x;
    const int blk = blockIdx.x;
    if (blk >= 1024) {                       // zero-padding blocks
        int idx4 = (blk - 1024) * 256 + tid; // [0, A)
        __builtin_nontemporal_store((v4f)(0.f), &out[idx4]);
        return;
    }
    if (blk < 256) {
        // fused gather + grouped conv1 (validated round 7 initial check)
        __shared__ float sg[32][34];
        int b  = blk >> 7;
        int g  = (blk >> 4) & 7;
        int l0 = (blk & 15) << 5;
        for (int t = tid; t < 32 * 34; t += 256) {
            int ch = t / 34;
            int j  = t - ch * 34;
            int l  = l0 + j - 1;
            int c  = (g << 5) + ch;
            sg[ch][j] = (l >= 0 && l < LL) ? feat[((b * CC + c) * LL + l) * LL + l] : 0.f;
        }
        __syncthreads();
        int ll = tid & 31;
        int os = tid >> 5;
        float a0[4] = {0.f, 0.f, 0.f, 0.f};
        float a1[4] = {0.f, 0.f, 0.f, 0.f};
        float a2[4] = {0.f, 0.f, 0.f, 0.f};
        const float* wbase = w1 + ((g << 5) + (os << 2)) * 96;
        #pragma unroll
        for (int i = 0; i < 32; ++i) {
            float dm = sg[i][ll];
            float d0 = sg[i][ll + 1];
            float dp = sg[i][ll + 2];
            #pragma unroll
            for (int it = 0; it < 4; ++it) {
                const float* wp = wbase + it * 96 + i * 3;
                a0[it] += dm * wp[0];
                a1[it] += d0 * wp[1];
                a2[it] += dp * wp[2];
            }
        }
        int l = l0 + ll;
        #pragma unroll
        for (int it = 0; it < 4; ++it) {
            int o = (g << 5) + (os << 2) + it;
            x1[((b * CC + o) << 9) + l] = gelu_exact(a0[it] + a1[it] + a2[it] + b1[o]);
        }
    } else {
        int idx = ((blk - 256) << 8) + tid;   // 768*256 = 196608 = C*C*3
        int o  = idx / 768;
        int ck = idx - o * 768;
        w2t[ck * CC + o] = w2[idx];
    }
}

// ---------------- K2: dense conv1d (+bias+GELU) -> x2, zero quads [A, B) ----
__global__ __launch_bounds__(256) void k2(
    const float* __restrict__ x1, const float* __restrict__ w2t,
    const float* __restrict__ b2, float* __restrict__ x2, v4f* __restrict__ out)
{
    const int tid = threadIdx.x;
    const int blk = blockIdx.x;
    if (blk >= 512) {
        int idx4 = A_QUADS + (blk - 512) * 256 + tid;  // [A, B)
        __builtin_nontemporal_store((v4f)(0.f), &out[idx4]);
        return;
    }
    __shared__ float s[CC][10];
    int oc = blk & 3;
    int lt = (blk >> 2) & 63;
    int b  = blk >> 8;
    int l0 = lt << 3;
    for (int t = tid; t < CC * 10; t += 256) {
        int c = t / 10;
        int j = t - c * 10;
        int p = l0 + j - 1;
        s[c][j] = (p >= 0 && p < LL) ? x1[((b * CC + c) << 9) + p] : 0.0f;
    }
    __syncthreads();
    int o  = (oc << 6) + (tid & 63);
    int jg = tid >> 6;
    float bias = b2[o];
    float acc0 = bias, acc1 = bias;
    const float* wp = w2t + o;
    #pragma unroll 4
    for (int c = 0; c < CC; ++c) {
        float w0  = wp[c * 768];
        float w1v = wp[c * 768 + 256];
        float w2v = wp[c * 768 + 512];
        float s0 = s[c][jg * 2 + 0];
        float s1 = s[c][jg * 2 + 1];
        float s2 = s[c][jg * 2 + 2];
        float s3 = s[c][jg * 2 + 3];
        acc0 += s0 * w0 + s1 * w1v + s2 * w2v;
        acc1 += s1 * w0 + s2 * w1v + s3 * w2v;
    }
    int l = l0 + jg * 2;
    float* xo = x2 + ((b * CC + o) << 9) + l;
    xo[0] = gelu_exact(acc0);
    xo[1] = gelu_exact(acc1);
}

// ---------------- K3: band pass for rows < ROWS_LO (quads already zeroed by
//                  K1/K2), plus fused zero-or-band for quads [B, N4) ---------
__global__ __launch_bounds__(256) void k3(
    const float* __restrict__ x2, const float* __restrict__ wb,
    float* __restrict__ outf, v4f* __restrict__ out)
{
    const int tid = threadIdx.x;
    const int blk = blockIdx.x;
    if (blk < BANDBLK) {
        int row = blk * 256 + tid;           // bc*512 + i
        if (row >= ROWS_LO) return;
        int i  = row & (LL - 1);
        int bc = row >> 9;
        const float* xr = x2 + (bc << 9);
        float xm = (i > 0)      ? xr[i - 1] : 0.f;
        float x0 = xr[i];
        float xp = (i < LL - 1) ? xr[i + 1] : 0.f;
        const float* w = wb + (bc & (CC - 1)) * 9;   // w_blur[c,0,ki,kj]
        float v0 = w[2] * xm;                         // j = i-2
        float v1 = w[1] * xm + w[5] * x0;             // j = i-1
        float v2 = w[0] * xm + w[4] * x0 + w[8] * xp; // j = i
        float v3 = w[3] * x0 + w[7] * xp;             // j = i+1
        float v4 = w[6] * xp;                         // j = i+2
        float* r = outf + ((long long)row << 9);
        if (i >= 2)      r[i - 2] = v0;
        if (i >= 1)      r[i - 1] = v1;
        r[i] = v2;
        if (i <= LL - 2) r[i + 1] = v3;
        if (i <= LL - 3) r[i + 2] = v4;
        return;
    }
    int idx4 = B_QUADS + (blk - BANDBLK) * 256 + tid;  // [B, N4)
    int row = idx4 >> 7;
    int i   = row & (LL - 1);
    int d0  = ((idx4 & 127) << 2) - i;
    v4f v = (v4f)(0.f);
    if ((unsigned)(d0 + 5) <= 7u) {
        int bc = row >> 9;
        const float* xr = x2 + (bc << 9);
        float xm = (i > 0)      ? xr[i - 1] : 0.f;
        float x0 = xr[i];
        float xp = (i < LL - 1) ? xr[i + 1] : 0.f;
        const float* w = wb + (bc & (CC - 1)) * 9;
        #pragma unroll
        for (int t = 0; t < 4; ++t) {
            int d = d0 + t;
            float r = 0.f;
            if (d == -2)      r = w[2] * xm;
            else if (d == -1) r = w[1] * xm + w[5] * x0;
            else if (d == 0)  r = w[0] * xm + w[4] * x0 + w[8] * xp;
            else if (d == 1)  r = w[3] * x0 + w[7] * xp;
            else if (d == 2)  r = w[6] * xp;
            v[t] = r;
        }
    }
    __builtin_nontemporal_store(v, &out[idx4]);
}

extern "C" void kernel_launch(void* const* d_in, const int* in_sizes, int n_in,
                              void* d_out, int out_size, void* d_ws, size_t ws_size,
                              hipStream_t stream) {
    const float* feat   = (const float*)d_in[0];
    const float* w1     = (const float*)d_in[1];
    const float* b1     = (const float*)d_in[2];
    const float* w2     = (const float*)d_in[3];
    const float* b2     = (const float*)d_in[4];
    const float* w_blur = (const float*)d_in[5];
    float* ws = (float*)d_ws;

    const int N = BB * CC * LL;      // 262144
    float* x1  = ws;                 // [N]
    float* x2  = ws + N;             // [N]
    float* w2t = ws + 2 * N;         // [C*C*3]

    k1<<<1024 + ZBLK, 256, 0, stream>>>(feat, w1, b1, w2, x1, w2t, (v4f*)d_out);
    k2<<<512 + ZBLK, 256, 0, stream>>>(x1, w2t, b2, x2, (v4f*)d_out);
    k3<<<BANDBLK + K3_FUSED, 256, 0, stream>>>(x2, w_blur, (float*)d_out, (v4f*)d_out);
}